// Round 9
// baseline (560.184 us; speedup 1.0000x reference)
//
#include <hip/hip_runtime.h>
#include <hip/hip_fp16.h>

// Pipeline (all fp16 MFMA, f32 accum):
//   cvt Wq,Wk,Wv (tiny) ;
//   k = e(f32)@Wk^T+bk -> slot2   (projf32: A reg-staged f32->f16, B gload_lds)
//   q = b(f32)@Wq^T+bq -> slot3 ; v = b(f32)@Wv^T+bv -> slot4 [BT,608]
//   attn = tanh(q@k^T) -> slot1, batched (R7 3-stage kernel, batch->XCD)
//   out  = attn@v^T -> f32 d_out, batched
//
// projf32 (3-stage, 128x128, BK=32, 4 waves):
//   body j: issue A(j+2) f32 loads (4 dwordx4, sets X/Y alternate) ;
//           vmcnt(6) [retires B(j)+A(j+1)] ; lgkmcnt(0) ; s_barrier ; schedbar ;
//           gload B(j+2) -> bS ; COMPUTE(bR) ; cvt A(j+1) -> ds_write bW ; rotate.
//   Write-after-read safety: bW last read 2 barriers earlier; bS last read
//   before this body's barrier (reads complete before MFMA issue => before
//   barrier arrival). B(j) publication: per-wave vmcnt(6) + barrier rendezvous.
// LDS slot swizzle (verified R6/R7): chunk c -> row c>>2, col ((c&3)^((c>>3)&3))*8;
// read lane l row r: chunk r*4 + ((l>>4)^((r>>1)&3)). Conflict-free + coalesced.

typedef _Float16 f16x8 __attribute__((ext_vector_type(8)));
typedef float f32x4 __attribute__((ext_vector_type(4)));

__global__ void cvt8_kernel(const float* __restrict__ src, _Float16* __restrict__ dst,
                            long long n8) {
    long long i = blockIdx.x * (long long)blockDim.x + threadIdx.x;
    const long long stride = gridDim.x * (long long)blockDim.x;
    for (; i < n8; i += stride) {
        const float4 f0 = ((const float4*)src)[2 * i];
        const float4 f1 = ((const float4*)src)[2 * i + 1];
        f16x8 h;
        h[0] = (_Float16)f0.x; h[1] = (_Float16)f0.y; h[2] = (_Float16)f0.z; h[3] = (_Float16)f0.w;
        h[4] = (_Float16)f1.x; h[5] = (_Float16)f1.y; h[6] = (_Float16)f1.z; h[7] = (_Float16)f1.w;
        ((f16x8*)dst)[i] = h;
    }
}

__device__ __forceinline__ void gload16(const _Float16* g, _Float16* l) {
    __builtin_amdgcn_global_load_lds(
        (const __attribute__((address_space(1))) unsigned int*)(g),
        (__attribute__((address_space(3))) unsigned int*)(l),
        16, 0, 0);
}

#define PACK8(h, f0, f1)                                                        \
    do {                                                                        \
        h[0] = (_Float16)(f0).x; h[1] = (_Float16)(f0).y;                       \
        h[2] = (_Float16)(f0).z; h[3] = (_Float16)(f0).w;                       \
        h[4] = (_Float16)(f1).x; h[5] = (_Float16)(f1).y;                       \
        h[6] = (_Float16)(f1).z; h[7] = (_Float16)(f1).w;                       \
    } while (0)

// ------------- projf32: A f32 reg-staged, B f16 gload_lds, 3-stage -----------
__global__ __launch_bounds__(256)
void projf32(const float* __restrict__ A, const _Float16* __restrict__ Bt,
             const float* __restrict__ bias, _Float16* __restrict__ C,
             int M, int Nreal, int Nstore, int K,
             int lda, int ldb, int ldc, int nTileN)
{
    __shared__ __align__(16) _Float16 lds[3 * 8192];   // 3 x (A 4096 + B 4096) hw

    int bid = blockIdx.x;
    {   // bijective XCD chunking (m204)
        const int nwg = gridDim.x;
        const int q8 = nwg >> 3, r8 = nwg & 7;
        const int xcd = bid & 7, loc = bid >> 3;
        bid = (xcd < r8 ? xcd * (q8 + 1) : r8 * (q8 + 1) + (xcd - r8) * q8) + loc;
    }
    const int tm = bid / nTileN, tn = bid - tm * nTileN;
    const int m0 = tm << 7, n0 = tn << 7;

    const int tid = threadIdx.x;
    const int lane = tid & 63;
    const int wid = tid >> 6;
    const int wm = wid >> 1, wn = wid & 1;

    // staging decode: thread owns slots tid, tid+256; swizzled col
    const int r0 = tid >> 2;
    const int c0 = (((tid & 3) ^ ((tid >> 3) & 3)) << 3);
    const int rA0 = (m0 + r0      < M ? m0 + r0      : M - 1);
    const int rA1 = (m0 + r0 + 64 < M ? m0 + r0 + 64 : M - 1);
    const int rB0 = (n0 + r0      < Nreal ? n0 + r0      : Nreal - 1);
    const int rB1 = (n0 + r0 + 64 < Nreal ? n0 + r0 + 64 : Nreal - 1);
    const float* pA0f = A + (size_t)rA0 * lda + c0;
    const float* pA1f = A + (size_t)rA1 * lda + c0;
    const _Float16* pB0 = Bt + (size_t)rB0 * ldb + c0;
    const _Float16* pB1 = Bt + (size_t)rB1 * ldb + c0;

    const int o0 = tid * 8, o1 = (tid + 256) * 8;

    // fragment read offsets
    const int rr = lane & 15;
    const int hh = lane >> 4;
    const int sw = (rr >> 1) & 3;
    const int fAo = ((wm * 64 + rr) * 4 + (hh ^ sw)) * 8;
    const int fBo = ((wn * 64 + rr) * 4 + (hh ^ sw)) * 8;

    const f32x4 z4 = {0.f, 0.f, 0.f, 0.f};
    f32x4 acc[4][4];
#pragma unroll
    for (int i = 0; i < 4; ++i)
#pragma unroll
        for (int j = 0; j < 4; ++j) acc[i][j] = z4;

    const int nt = K >> 5;   // 24 for K=768

#define COMPUTE(off)                                                           \
    do {                                                                       \
        const _Float16* cA_ = lds + (off);                                     \
        const _Float16* cB_ = cA_ + 4096;                                      \
        f16x8 a_[4], b_[4];                                                    \
        _Pragma("unroll")                                                      \
        for (int mi = 0; mi < 4; ++mi) a_[mi] = *(const f16x8*)(cA_ + fAo + mi * 512); \
        _Pragma("unroll")                                                      \
        for (int ni = 0; ni < 4; ++ni) b_[ni] = *(const f16x8*)(cB_ + fBo + ni * 512); \
        _Pragma("unroll")                                                      \
        for (int mi = 0; mi < 4; ++mi)                                         \
            _Pragma("unroll")                                                  \
            for (int ni = 0; ni < 4; ++ni)                                     \
                acc[mi][ni] = __builtin_amdgcn_mfma_f32_16x16x32_f16(          \
                    a_[mi], b_[ni], acc[mi][ni], 0, 0, 0);                     \
    } while (0)

    // PBODY: cur set c* holds A(j+1); n* receives A(j+2)
#define PBODY(ca0, ca1, ca2, ca3, na0, na1, na2, na3, J)                       \
    do {                                                                       \
        const int ko2_ = ((J) + 2) << 5;                                       \
        if ((J) + 2 < nt) {                                                    \
            na0 = *(const float4*)(pA0f + ko2_);                               \
            na1 = *(const float4*)(pA0f + ko2_ + 4);                           \
            na2 = *(const float4*)(pA1f + ko2_);                               \
            na3 = *(const float4*)(pA1f + ko2_ + 4);                           \
        }                                                                      \
        asm volatile("s_waitcnt vmcnt(6)" ::: "memory");                       \
        asm volatile("s_waitcnt lgkmcnt(0)" ::: "memory");                     \
        __builtin_amdgcn_s_barrier();                                          \
        __builtin_amdgcn_sched_barrier(0);                                     \
        if ((J) + 2 < nt) {                                                    \
            gload16(pB0 + ko2_, lds + bS + 4096 + o0);                         \
            gload16(pB1 + ko2_, lds + bS + 4096 + o1);                         \
        }                                                                      \
        COMPUTE(bR);                                                           \
        {                                                                      \
            f16x8 h0_, h1_;                                                    \
            PACK8(h0_, ca0, ca1);                                              \
            PACK8(h1_, ca2, ca3);                                              \
            *(f16x8*)(lds + bW + o0) = h0_;                                    \
            *(f16x8*)(lds + bW + o1) = h1_;                                    \
        }                                                                      \
        { const int tr_ = bR; bR = bW; bW = bS; bS = tr_; }                    \
    } while (0)

    float4 x0, x1, x2, x3, y0, y1, y2, y3;

    // prologue: A(0)->X, B(0)->buf0.B, B(1)->buf1.B, cvt A(0)->buf0.A, A(1)->X
    x0 = *(const float4*)(pA0f);     x1 = *(const float4*)(pA0f + 4);
    x2 = *(const float4*)(pA1f);     x3 = *(const float4*)(pA1f + 4);
    gload16(pB0, lds + 4096 + o0);       gload16(pB1, lds + 4096 + o1);
    gload16(pB0 + 32, lds + 12288 + o0); gload16(pB1 + 32, lds + 12288 + o1);
    {
        f16x8 h0_, h1_;
        PACK8(h0_, x0, x1);
        PACK8(h1_, x2, x3);
        *(f16x8*)(lds + o0) = h0_;
        *(f16x8*)(lds + o1) = h1_;
    }
    x0 = *(const float4*)(pA0f + 32); x1 = *(const float4*)(pA0f + 36);
    x2 = *(const float4*)(pA1f + 32); x3 = *(const float4*)(pA1f + 36);

    int bR = 0, bW = 8192, bS = 16384;

    for (int j = 0; j < nt - 1; ++j) {
        if ((j & 1) == 0) PBODY(x0, x1, x2, x3, y0, y1, y2, y3, j);
        else              PBODY(y0, y1, y2, y3, x0, x1, x2, x3, j);
    }
    // final tile nt-1
    asm volatile("s_waitcnt vmcnt(0)" ::: "memory");
    asm volatile("s_waitcnt lgkmcnt(0)" ::: "memory");
    __builtin_amdgcn_s_barrier();
    __builtin_amdgcn_sched_barrier(0);
    COMPUTE(bR);

#undef PBODY
#undef COMPUTE

    // epilogue: bias -> f16 store (zero padded cols [Nreal, Nstore))
    const int cr0 = (lane >> 4) << 2;
    const int cc = lane & 15;
#pragma unroll
    for (int mi = 0; mi < 4; ++mi) {
#pragma unroll
        for (int ni = 0; ni < 4; ++ni) {
            const int gc = n0 + wn * 64 + ni * 16 + cc;
            if (gc >= Nstore) continue;
            const bool real = gc < Nreal;
            const float bb = real ? bias[gc] : 0.f;
#pragma unroll
            for (int r = 0; r < 4; ++r) {
                const int gr = m0 + wm * 64 + mi * 16 + cr0 + r;
                if (gr >= M) continue;
                const float x = real ? (acc[mi][ni][r] + bb) : 0.f;
                C[(size_t)gr * ldc + gc] = (_Float16)x;
            }
        }
    }
}

// -------- batched 128x128 / BK=32 / 3-stage kernel (R7, unchanged) ----------
template<bool TANH, bool OUT_F16, bool BIAS, int MODE>
__global__ __launch_bounds__(256)
void gemm_nt_f16(const _Float16* __restrict__ A, const _Float16* __restrict__ Bt,
                 const float* __restrict__ bias, void* __restrict__ Cp,
                 int M, int Nreal, int Nstore, int K,
                 int lda, int ldb, int ldc, int nTileN, int nTiles,
                 long long sA, long long sB, long long sC)
{
    __shared__ __align__(16) _Float16 lds[3 * 8192];

    int bid = blockIdx.x;
    int z, tm, tn;
    if (MODE == 0) {
        const int nwg = gridDim.x;
        const int q8 = nwg >> 3, r8 = nwg & 7;
        const int xcd = bid & 7, loc = bid >> 3;
        bid = (xcd < r8 ? xcd * (q8 + 1) : r8 * (q8 + 1) + (xcd - r8) * q8) + loc;
        z = 0;
        tm = bid / nTileN; tn = bid - tm * nTileN;
    } else {
        const int xcd = bid & 7, idx = bid >> 3;
        const int g = idx / nTiles, tile = idx - g * nTiles;
        z = g * 8 + xcd;
        tm = tile / nTileN; tn = tile - tm * nTileN;
    }
    const int m0 = tm << 7, n0 = tn << 7;

    const _Float16* Az = A + (size_t)z * sA;
    const _Float16* Bz = Bt + (size_t)z * sB;

    const int tid = threadIdx.x;
    const int lane = tid & 63;
    const int wid = tid >> 6;
    const int wm = wid >> 1, wn = wid & 1;

    const int r0 = tid >> 2;
    const int c0 = (((tid & 3) ^ ((tid >> 3) & 3)) << 3);
    const int rA0 = (m0 + r0      < M ? m0 + r0      : M - 1);
    const int rA1 = (m0 + r0 + 64 < M ? m0 + r0 + 64 : M - 1);
    const int rB0 = (n0 + r0      < Nreal ? n0 + r0      : Nreal - 1);
    const int rB1 = (n0 + r0 + 64 < Nreal ? n0 + r0 + 64 : Nreal - 1);
    const _Float16* pA0 = Az + (size_t)rA0 * lda + c0;
    const _Float16* pA1 = Az + (size_t)rA1 * lda + c0;
    const _Float16* pB0 = Bz + (size_t)rB0 * ldb + c0;
    const _Float16* pB1 = Bz + (size_t)rB1 * ldb + c0;

    const int o0 = tid * 8, o1 = (tid + 256) * 8;

    const int rr = lane & 15;
    const int hh = lane >> 4;
    const int sw = (rr >> 1) & 3;
    const int fAo = ((wm * 64 + rr) * 4 + (hh ^ sw)) * 8;
    const int fBo = ((wn * 64 + rr) * 4 + (hh ^ sw)) * 8;

    const f32x4 z4 = {0.f, 0.f, 0.f, 0.f};
    f32x4 acc[4][4];
#pragma unroll
    for (int i = 0; i < 4; ++i)
#pragma unroll
        for (int j = 0; j < 4; ++j) acc[i][j] = z4;

    const int nt = K >> 5;

#define STAGE(si, kt)                                              \
    do {                                                           \
        _Float16* base_ = lds + (si) * 8192;                       \
        const int ko_ = (kt) << 5;                                 \
        gload16(pA0 + ko_, base_ + o0);                            \
        gload16(pA1 + ko_, base_ + o1);                            \
        gload16(pB0 + ko_, base_ + 4096 + o0);                     \
        gload16(pB1 + ko_, base_ + 4096 + o1);                     \
    } while (0)

#define COMPUTE(si)                                                            \
    do {                                                                       \
        const _Float16* cA_ = lds + (si) * 8192;                               \
        const _Float16* cB_ = cA_ + 4096;                                      \
        f16x8 a_[4], b_[4];                                                    \
        _Pragma("unroll")                                                      \
        for (int mi = 0; mi < 4; ++mi) a_[mi] = *(const f16x8*)(cA_ + fAo + mi * 512); \
        _Pragma("unroll")                                                      \
        for (int ni = 0; ni < 4; ++ni) b_[ni] = *(const f16x8*)(cB_ + fBo + ni * 512); \
        _Pragma("unroll")                                                      \
        for (int mi = 0; mi < 4; ++mi)                                         \
            _Pragma("unroll")                                                  \
            for (int ni = 0; ni < 4; ++ni)                                     \
                acc[mi][ni] = __builtin_amdgcn_mfma_f32_16x16x32_f16(          \
                    a_[mi], b_[ni], acc[mi][ni], 0, 0, 0);                     \
    } while (0)

    STAGE(0, 0);
    STAGE(1, 1);

    for (int j = 0; j < nt - 1; ++j) {
        asm volatile("s_waitcnt vmcnt(4)" ::: "memory");
        __builtin_amdgcn_s_barrier();
        __builtin_amdgcn_sched_barrier(0);
        if (j + 2 < nt) STAGE((j + 2) % 3, j + 2);
        COMPUTE(j % 3);
    }
    asm volatile("s_waitcnt vmcnt(0)" ::: "memory");
    __builtin_amdgcn_s_barrier();
    __builtin_amdgcn_sched_barrier(0);
    COMPUTE((nt - 1) % 3);

#undef STAGE
#undef COMPUTE

    const int cr0 = (lane >> 4) << 2;
    const int cc = lane & 15;
    float*    Cf = (float*)Cp    + (size_t)z * sC;
    _Float16* Ch = (_Float16*)Cp + (size_t)z * sC;
#pragma unroll
    for (int mi = 0; mi < 4; ++mi) {
#pragma unroll
        for (int ni = 0; ni < 4; ++ni) {
            const int gc = n0 + wn * 64 + ni * 16 + cc;
            if (gc >= Nstore) continue;
            const bool real = gc < Nreal;
            float bb = 0.f;
            if (BIAS) bb = real ? bias[gc] : 0.f;
#pragma unroll
            for (int r = 0; r < 4; ++r) {
                const int gr = m0 + wm * 64 + mi * 16 + cr0 + r;
                if (gr >= M) continue;
                float x = real ? (acc[mi][ni][r] + bb) : 0.f;
                if (TANH) x = tanhf(x);
                if (OUT_F16) Ch[(size_t)gr * ldc + gc] = (_Float16)x;
                else         Cf[(size_t)gr * ldc + gc] = x;
            }
        }
    }
}

extern "C" void kernel_launch(void* const* d_in, const int* in_sizes, int n_in,
                              void* d_out, int out_size, void* d_ws, size_t ws_size,
                              hipStream_t stream)
{
    const float* b  = (const float*)d_in[0];
    const float* e  = (const float*)d_in[1];
    const float* Wq = (const float*)d_in[2];
    const float* bq = (const float*)d_in[3];
    const float* Wk = (const float*)d_in[4];
    const float* bk = (const float*)d_in[5];
    const float* Wv = (const float*)d_in[6];
    const float* bv = (const float*)d_in[7];
    float* out = (float*)d_out;

    const int BT = 36928, D = 768, T = 577, S = 577, Sp = 608;

    _Float16* Wq_h  = (_Float16*)d_ws;
    _Float16* Wk_h  = Wq_h + 589824;
    _Float16* Wv_h  = Wk_h + 589824;
    _Float16* slot1 = Wv_h + 443136;                 // at_h
    _Float16* slot2 = slot1 + (size_t)BT * D;        // k_h
    _Float16* slot3 = slot2 + (size_t)BT * D;        // q_h
    _Float16* slot4 = slot3 + (size_t)BT * D;        // v_h [BT,608]

    cvt8_kernel<<<288, 256, 0, stream>>>(Wq, Wq_h, 73728);
    cvt8_kernel<<<288, 256, 0, stream>>>(Wk, Wk_h, 73728);
    cvt8_kernel<<<217, 256, 0, stream>>>(Wv, Wv_h, 55392);

    // k = e@Wk^T + bk   [BT,768]  (A = e f32 direct)
    projf32<<<dim3(1734, 1, 1), 256, 0, stream>>>(
        e, Wk_h, bk, slot2, BT, D, D, D, D, D, D, 6);
    // q = b@Wq^T + bq   [BT,768]
    projf32<<<dim3(1734, 1, 1), 256, 0, stream>>>(
        b, Wq_h, bq, slot3, BT, D, D, D, D, D, D, 6);
    // v = b@Wv^T + bv   [BT,608] (cols 577..607 zeroed)
    projf32<<<dim3(1445, 1, 1), 256, 0, stream>>>(
        b, Wv_h, bv, slot4, BT, S, Sp, D, D, D, Sp, 5);
    // attn = tanh(q@k^T) -> slot1  batched [64][577,608]
    gemm_nt_f16<true, true, false, 1><<<dim3(1600, 1, 1), 256, 0, stream>>>(
        slot3, slot2, nullptr, slot1, T, S, Sp, D, D, D, Sp, 5, 25,
        (long long)T * D, (long long)T * D, (long long)T * Sp);
    // out = attn@v^T   batched [64][577,577] f32, K=608 (pads zero)
    gemm_nt_f16<false, false, false, 1><<<dim3(1600, 1, 1), 256, 0, stream>>>(
        slot1, slot4, nullptr, out, T, T, T, Sp, Sp, Sp, T, 5, 25,
        (long long)T * Sp, (long long)T * Sp, (long long)T * T);
}

// Round 10
// 384.953 us; speedup vs baseline: 1.4552x; 1.4552x over previous
//
#include <hip/hip_runtime.h>
#include <hip/hip_fp16.h>

// Pipeline (all fp16 MFMA, f32 accum), R7-proven 3-stage GEMM structure:
//   Algebraic fusion: q·k^T = b (Wq^T Wk) e^T + b·w1 + c2(e) + c0, with
//   w1 = Wq^T bk, w2 = Wk^T bq, c0 = bq·bk. So:
//     Mt[n,k] = (Wk^T Wq)[n,k] = NT(WkT, WqT)   [768x768 f16, tiny GEMM]
//     bm' = b @ [Mt | w1 | 0]^T + [0.. c0 1]   -> [BT, 800] (cols: 768 bM,
//           768: b·w1+c0, 769: 1, 770..799: 0)
//     e'  = [e_f16 | 1 | e·w2 | 0]             -> [BT, 800]
//     attn = tanh(NT(bm', e')) ; out = NT(attn, v) ; v = NT(b_h, Wv)+bv.
//   This REPLACES the q-proj and k-proj (saves one full 43.6 GFLOP GEMM).
// GEMMs: NT, 128x128 tile, BK=32, 3-stage counted-vmcnt pipeline (R7),
// XOR-swizzled LDS (0 bank conflicts + coalesced gload_lds writes),
// MODE0 = bijective XCD chunking; MODE1 = batch->XCD co-location.

typedef _Float16 f16x8 __attribute__((ext_vector_type(8)));
typedef _Float16 f16x4 __attribute__((ext_vector_type(4)));
typedef float f32x4 __attribute__((ext_vector_type(4)));

__global__ void cvt8_kernel(const float* __restrict__ src, _Float16* __restrict__ dst,
                            long long n8) {
    long long i = blockIdx.x * (long long)blockDim.x + threadIdx.x;
    const long long stride = gridDim.x * (long long)blockDim.x;
    for (; i < n8; i += stride) {
        const float4 f0 = ((const float4*)src)[2 * i];
        const float4 f1 = ((const float4*)src)[2 * i + 1];
        f16x8 h;
        h[0] = (_Float16)f0.x; h[1] = (_Float16)f0.y; h[2] = (_Float16)f0.z; h[3] = (_Float16)f0.w;
        h[4] = (_Float16)f1.x; h[5] = (_Float16)f1.y; h[6] = (_Float16)f1.z; h[7] = (_Float16)f1.w;
        ((f16x8*)dst)[i] = h;
    }
}

// f32 [768,768] -> f16 transposed [768,768]
__global__ void cvtT_kernel(const float* __restrict__ src, _Float16* __restrict__ dst) {
    __shared__ float t[32][33];
    const int bx = blockIdx.x, by = blockIdx.y;
    const int tx = threadIdx.x & 31, ty = threadIdx.x >> 5;
#pragma unroll
    for (int k = 0; k < 4; ++k) {
        const int r = ty + 8 * k;
        t[r][tx] = src[(size_t)(by * 32 + r) * 768 + bx * 32 + tx];
    }
    __syncthreads();
#pragma unroll
    for (int k = 0; k < 4; ++k) {
        const int r = ty + 8 * k;
        dst[(size_t)(bx * 32 + r) * 768 + by * 32 + tx] = (_Float16)t[tx][r];
    }
}

// w1 -> Mt_aug row 768 ; w2f ; c0+bias_aug ; zero Mt_aug rows 769..799
__global__ void prep_kernel(const _Float16* __restrict__ WqT, const _Float16* __restrict__ WkT,
                            const float* __restrict__ bq, const float* __restrict__ bk,
                            float* __restrict__ w2f, _Float16* __restrict__ Mt_aug,
                            float* __restrict__ bias_aug) {
    const int wid = blockIdx.x * 4 + (threadIdx.x >> 6);
    const int lane = threadIdx.x & 63;
    if (wid < 768) {                 // w1[wid] = WqT[wid,:]·bk
        float s = 0.f;
        for (int k = 0; k < 12; ++k) s += (float)WqT[(size_t)wid * 768 + lane + 64 * k] * bk[lane + 64 * k];
        for (int o = 32; o; o >>= 1) s += __shfl_xor(s, o);
        if (lane == 0) Mt_aug[(size_t)768 * 768 + wid] = (_Float16)s;
    } else if (wid < 1536) {         // w2[n] = WkT[n,:]·bq
        const int n = wid - 768;
        float s = 0.f;
        for (int k = 0; k < 12; ++k) s += (float)WkT[(size_t)n * 768 + lane + 64 * k] * bq[lane + 64 * k];
        for (int o = 32; o; o >>= 1) s += __shfl_xor(s, o);
        if (lane == 0) w2f[n] = s;
    } else if (wid == 1536) {        // c0 and bias_aug
        float s = 0.f;
        for (int k = 0; k < 12; ++k) s += bq[lane + 64 * k] * bk[lane + 64 * k];
        for (int o = 32; o; o >>= 1) s += __shfl_xor(s, o);
        for (int k = 0; k < 12; ++k) bias_aug[lane + 64 * k] = 0.f;
        if (lane < 32) {
            float v = 0.f;
            if (lane == 0) v = s;    // bias[768] = c0
            if (lane == 1) v = 1.f;  // bias[769] = 1
            bias_aug[768 + lane] = v;
        }
    } else if (wid < 1568) {         // zero rows 769..799
        const int r = 769 + (wid - 1537);
        if (r < 800)
            for (int k = 0; k < 12; ++k) Mt_aug[(size_t)r * 768 + lane + 64 * k] = (_Float16)0.f;
    }
}

// e f32 [rows,768] -> e' f16 [rows,800]: cvt + col768=1 + col769=e·w2 + 770..799=0
__global__ void cvt_e_aug_kernel(const float* __restrict__ e, const float* __restrict__ w2f,
                                 _Float16* __restrict__ dst, int rows) {
    const int wpb = blockDim.x >> 6;
    int wid = blockIdx.x * wpb + (threadIdx.x >> 6);
    const int nw = gridDim.x * wpb;
    const int lane = threadIdx.x & 63;
    for (int s = wid; s < rows; s += nw) {
        const float4* er = (const float4*)(e + (size_t)s * 768);
        _Float16* dr = dst + (size_t)s * 800;
        float dot = 0.f;
#pragma unroll
        for (int k = 0; k < 3; ++k) {
            const int idx = lane + 64 * k;
            const float4 v = er[idx];
            const float4 w = ((const float4*)w2f)[idx];
            dot += v.x * w.x + v.y * w.y + v.z * w.z + v.w * w.w;
            f16x4 h;
            h[0] = (_Float16)v.x; h[1] = (_Float16)v.y;
            h[2] = (_Float16)v.z; h[3] = (_Float16)v.w;
            *(f16x4*)(dr + 4 * idx) = h;
        }
        for (int o = 32; o; o >>= 1) dot += __shfl_xor(dot, o);
        if (lane < 32) {
            _Float16 v = (_Float16)0.f;
            if (lane == 0) v = (_Float16)1.f;
            if (lane == 1) v = (_Float16)dot;
            dr[768 + lane] = v;
        }
    }
}

__device__ __forceinline__ void gload16(const _Float16* g, _Float16* l) {
    __builtin_amdgcn_global_load_lds(
        (const __attribute__((address_space(1))) unsigned int*)(g),
        (__attribute__((address_space(3))) unsigned int*)(l),
        16, 0, 0);
}

// -------- 128x128 / BK=32 / 3-stage counted-vmcnt GEMM (R7, proven) ----------
template<bool TANH, bool OUT_F16, bool BIAS, int MODE>
__global__ __launch_bounds__(256)
void gemm_nt_f16(const _Float16* __restrict__ A, const _Float16* __restrict__ Bt,
                 const float* __restrict__ bias, void* __restrict__ Cp,
                 int M, int Nreal, int Nstore, int K,
                 int lda, int ldb, int ldc, int nTileN, int nTiles,
                 long long sA, long long sB, long long sC)
{
    __shared__ __align__(16) _Float16 lds[3 * 8192];

    int bid = blockIdx.x;
    int z, tm, tn;
    if (MODE == 0) {
        const int nwg = gridDim.x;
        const int q8 = nwg >> 3, r8 = nwg & 7;
        const int xcd = bid & 7, loc = bid >> 3;
        bid = (xcd < r8 ? xcd * (q8 + 1) : r8 * (q8 + 1) + (xcd - r8) * q8) + loc;
        z = 0;
        tm = bid / nTileN; tn = bid - tm * nTileN;
    } else {
        const int xcd = bid & 7, idx = bid >> 3;
        const int g = idx / nTiles, tile = idx - g * nTiles;
        z = g * 8 + xcd;
        tm = tile / nTileN; tn = tile - tm * nTileN;
    }
    const int m0 = tm << 7, n0 = tn << 7;

    const _Float16* Az = A + (size_t)z * sA;
    const _Float16* Bz = Bt + (size_t)z * sB;

    const int tid = threadIdx.x;
    const int lane = tid & 63;
    const int wid = tid >> 6;
    const int wm = wid >> 1, wn = wid & 1;

    const int r0 = tid >> 2;
    const int c0 = (((tid & 3) ^ ((tid >> 3) & 3)) << 3);
    const int rA0 = (m0 + r0      < M ? m0 + r0      : M - 1);
    const int rA1 = (m0 + r0 + 64 < M ? m0 + r0 + 64 : M - 1);
    const int rB0 = (n0 + r0      < Nreal ? n0 + r0      : Nreal - 1);
    const int rB1 = (n0 + r0 + 64 < Nreal ? n0 + r0 + 64 : Nreal - 1);
    const _Float16* pA0 = Az + (size_t)rA0 * lda + c0;
    const _Float16* pA1 = Az + (size_t)rA1 * lda + c0;
    const _Float16* pB0 = Bz + (size_t)rB0 * ldb + c0;
    const _Float16* pB1 = Bz + (size_t)rB1 * ldb + c0;

    const int o0 = tid * 8, o1 = (tid + 256) * 8;

    const int rr = lane & 15;
    const int hh = lane >> 4;
    const int sw = (rr >> 1) & 3;
    const int fAo = ((wm * 64 + rr) * 4 + (hh ^ sw)) * 8;
    const int fBo = ((wn * 64 + rr) * 4 + (hh ^ sw)) * 8;

    const f32x4 z4 = {0.f, 0.f, 0.f, 0.f};
    f32x4 acc[4][4];
#pragma unroll
    for (int i = 0; i < 4; ++i)
#pragma unroll
        for (int j = 0; j < 4; ++j) acc[i][j] = z4;

    const int nt = K >> 5;

#define STAGE(si, kt)                                              \
    do {                                                           \
        _Float16* base_ = lds + (si) * 8192;                       \
        const int ko_ = (kt) << 5;                                 \
        gload16(pA0 + ko_, base_ + o0);                            \
        gload16(pA1 + ko_, base_ + o1);                            \
        gload16(pB0 + ko_, base_ + 4096 + o0);                     \
        gload16(pB1 + ko_, base_ + 4096 + o1);                     \
    } while (0)

#define COMPUTE(si)                                                            \
    do {                                                                       \
        const _Float16* cA_ = lds + (si) * 8192;                               \
        const _Float16* cB_ = cA_ + 4096;                                      \
        f16x8 a_[4], b_[4];                                                    \
        _Pragma("unroll")                                                      \
        for (int mi = 0; mi < 4; ++mi) a_[mi] = *(const f16x8*)(cA_ + fAo + mi * 512); \
        _Pragma("unroll")                                                      \
        for (int ni = 0; ni < 4; ++ni) b_[ni] = *(const f16x8*)(cB_ + fBo + ni * 512); \
        _Pragma("unroll")                                                      \
        for (int mi = 0; mi < 4; ++mi)                                         \
            _Pragma("unroll")                                                  \
            for (int ni = 0; ni < 4; ++ni)                                     \
                acc[mi][ni] = __builtin_amdgcn_mfma_f32_16x16x32_f16(          \
                    a_[mi], b_[ni], acc[mi][ni], 0, 0, 0);                     \
    } while (0)

    STAGE(0, 0);
    STAGE(1, 1);

    for (int j = 0; j < nt - 1; ++j) {
        asm volatile("s_waitcnt vmcnt(4)" ::: "memory");
        __builtin_amdgcn_s_barrier();
        __builtin_amdgcn_sched_barrier(0);
        if (j + 2 < nt) STAGE((j + 2) % 3, j + 2);
        COMPUTE(j % 3);
    }
    asm volatile("s_waitcnt vmcnt(0)" ::: "memory");
    __builtin_amdgcn_s_barrier();
    __builtin_amdgcn_sched_barrier(0);
    COMPUTE((nt - 1) % 3);

#undef STAGE
#undef COMPUTE

    const int cr0 = (lane >> 4) << 2;
    const int cc = lane & 15;
    float*    Cf = (float*)Cp    + (size_t)z * sC;
    _Float16* Ch = (_Float16*)Cp + (size_t)z * sC;
#pragma unroll
    for (int mi = 0; mi < 4; ++mi) {
#pragma unroll
        for (int ni = 0; ni < 4; ++ni) {
            const int gc = n0 + wn * 64 + ni * 16 + cc;
            if (gc >= Nstore) continue;
            const bool real = gc < Nreal;
            float bb = 0.f;
            if (BIAS) bb = real ? bias[gc] : 0.f;
#pragma unroll
            for (int r = 0; r < 4; ++r) {
                const int gr = m0 + wm * 64 + mi * 16 + cr0 + r;
                if (gr >= M) continue;
                float x = real ? (acc[mi][ni][r] + bb) : 0.f;
                if (TANH) x = tanhf(x);
                if (OUT_F16) Ch[(size_t)gr * ldc + gc] = (_Float16)x;
                else         Cf[(size_t)gr * ldc + gc] = x;
            }
        }
    }
}

extern "C" void kernel_launch(void* const* d_in, const int* in_sizes, int n_in,
                              void* d_out, int out_size, void* d_ws, size_t ws_size,
                              hipStream_t stream)
{
    const float* b  = (const float*)d_in[0];
    const float* e  = (const float*)d_in[1];
    const float* Wq = (const float*)d_in[2];
    const float* bq = (const float*)d_in[3];
    const float* Wk = (const float*)d_in[4];
    const float* bk = (const float*)d_in[5];
    const float* Wv = (const float*)d_in[6];
    const float* bv = (const float*)d_in[7];
    float* out = (float*)d_out;

    const int BT = 36928, T = 577, S = 577, Sp = 608, Kb = 800;

    // ws layout (f16 units): ~212.5 MB total
    _Float16* WqT_h   = (_Float16*)d_ws;                     // 589824
    _Float16* WkT_h   = WqT_h + 589824;                      // 589824
    _Float16* Wv_h    = WkT_h + 589824;                      // 443136
    _Float16* Mt_aug  = Wv_h + 443136;                       // 800*768
    float*    bias_aug = (float*)(Mt_aug + 614400);          // 800 f32 (1600 hw)
    float*    w2f      = (float*)((_Float16*)bias_aug + 1600); // 768 f32 (1536 hw)
    _Float16* S1 = (_Float16*)w2f + 1536;                    // b_h then e_aug [BT,800]
    _Float16* S2 = S1 + (size_t)BT * Kb;                     // v   [BT,608]
    _Float16* S3 = S2 + (size_t)BT * Sp;                     // bm' [BT,800]
    _Float16* S4 = S3 + (size_t)BT * Kb;                     // attn [BT,608]

    // weight preprocessing
    cvtT_kernel<<<dim3(24, 24), 256, 0, stream>>>(Wq, WqT_h);
    cvtT_kernel<<<dim3(24, 24), 256, 0, stream>>>(Wk, WkT_h);
    cvt8_kernel<<<217, 256, 0, stream>>>(Wv, Wv_h, 55392);
    prep_kernel<<<392, 256, 0, stream>>>(WqT_h, WkT_h, bq, bk, w2f, Mt_aug, bias_aug);
    // Mt = NT(WkT, WqT)  [768x768] -> Mt_aug rows 0..767
    gemm_nt_f16<false, true, false, 0><<<dim3(36, 1, 1), 256, 0, stream>>>(
        WkT_h, WqT_h, nullptr, Mt_aug, 768, 768, 768, 768, 768, 768, 768, 6, 0, 0, 0, 0);

    // b -> f16
    cvt8_kernel<<<2048, 256, 0, stream>>>(b, S1, 3545088);
    // v = b@Wv^T + bv   [BT,608]
    gemm_nt_f16<false, true, true, 0><<<dim3(1445, 1, 1), 256, 0, stream>>>(
        S1, Wv_h, bv, S2, BT, S, Sp, 768, 768, 768, Sp, 5, 0, 0, 0, 0);
    // bm' = b@Mt_aug^T + bias_aug   [BT,800]
    gemm_nt_f16<false, true, true, 0><<<dim3(2023, 1, 1), 256, 0, stream>>>(
        S1, Mt_aug, bias_aug, S3, BT, Kb, Kb, 768, 768, 768, Kb, 7, 0, 0, 0, 0);
    // e' (overwrites b_h, dead)
    cvt_e_aug_kernel<<<2048, 256, 0, stream>>>(e, w2f, S1, BT);
    // attn = tanh(NT(bm', e'))  batched [64][577,608], K=800
    gemm_nt_f16<true, true, false, 1><<<dim3(1600, 1, 1), 256, 0, stream>>>(
        S3, S1, nullptr, S4, T, S, Sp, Kb, Kb, Kb, Sp, 5, 25,
        (long long)T * Kb, (long long)T * Kb, (long long)T * Sp);
    // out = NT(attn, v)   batched [64][577,577] f32, K=608
    gemm_nt_f16<false, false, false, 1><<<dim3(1600, 1, 1), 256, 0, stream>>>(
        S4, S2, nullptr, out, T, T, T, Sp, Sp, Sp, T, 5, 25,
        (long long)T * Sp, (long long)T * Sp, (long long)T * T);
}

// Round 11
// 354.748 us; speedup vs baseline: 1.5791x; 1.0851x over previous
//
#include <hip/hip_runtime.h>
#include <hip/hip_fp16.h>

// Pipeline (all fp16 MFMA, f32 accum), R7-proven 3-stage GEMM structure:
//   Algebraic fusion (R10): q·k^T = b(Wq^T Wk)e^T + b·w1 + (e·w2) + c0.
//   This round: the v-proj and bm'-proj share A=b_h -> ONE merged GEMM:
//     B_merged rows = [Mt(768) | w1(1) | zeros(31) | Wv(577)] = 1377 rows
//     bias_mg = [0 x768 | c0 | 1 | 0 x30 | bv(577) | 0 x31]   (1408)
//     S_big = b_h @ B_merged^T + bias_mg   -> [BT,1408] f16
//       cols 0..799  = bm' (attn A-operand, lda=1408)
//       cols 800..1407 = v padded (out B-operand, base +800, ldb=1408)
//   attn = tanh(NT(S_big[,0:800], e'))  batched ; out = NT(attn, S_big[,800:])
// GEMMs: NT, 128x128 tile, BK=32, 3-stage counted-vmcnt pipeline (R7),
// XOR-swizzled LDS (0 bank conflicts + coalesced gload_lds writes),
// MODE0 = bijective XCD chunking; MODE1 = batch->XCD co-location.

typedef _Float16 f16x8 __attribute__((ext_vector_type(8)));
typedef _Float16 f16x4 __attribute__((ext_vector_type(4)));
typedef float f32x4 __attribute__((ext_vector_type(4)));

__global__ void cvt8_kernel(const float* __restrict__ src, _Float16* __restrict__ dst,
                            long long n8) {
    long long i = blockIdx.x * (long long)blockDim.x + threadIdx.x;
    const long long stride = gridDim.x * (long long)blockDim.x;
    for (; i < n8; i += stride) {
        const float4 f0 = ((const float4*)src)[2 * i];
        const float4 f1 = ((const float4*)src)[2 * i + 1];
        f16x8 h;
        h[0] = (_Float16)f0.x; h[1] = (_Float16)f0.y; h[2] = (_Float16)f0.z; h[3] = (_Float16)f0.w;
        h[4] = (_Float16)f1.x; h[5] = (_Float16)f1.y; h[6] = (_Float16)f1.z; h[7] = (_Float16)f1.w;
        ((f16x8*)dst)[i] = h;
    }
}

// two f32 [768,768] -> f16 transposed [768,768] (z selects matrix)
__global__ void cvtT2_kernel(const float* __restrict__ s0, _Float16* __restrict__ d0,
                             const float* __restrict__ s1, _Float16* __restrict__ d1) {
    __shared__ float t[32][33];
    const float* src = blockIdx.z ? s1 : s0;
    _Float16* dst = blockIdx.z ? d1 : d0;
    const int bx = blockIdx.x, by = blockIdx.y;
    const int tx = threadIdx.x & 31, ty = threadIdx.x >> 5;
#pragma unroll
    for (int k = 0; k < 4; ++k) {
        const int r = ty + 8 * k;
        t[r][tx] = src[(size_t)(by * 32 + r) * 768 + bx * 32 + tx];
    }
    __syncthreads();
#pragma unroll
    for (int k = 0; k < 4; ++k) {
        const int r = ty + 8 * k;
        dst[(size_t)(bx * 32 + r) * 768 + by * 32 + tx] = (_Float16)t[tx][r];
    }
}

// w1 -> Mt_aug row 768 ; w2f ; bias_mg[1408] ; zero Mt_aug rows 769..799
__global__ void prep_kernel(const _Float16* __restrict__ WqT, const _Float16* __restrict__ WkT,
                            const float* __restrict__ bq, const float* __restrict__ bk,
                            const float* __restrict__ bv,
                            float* __restrict__ w2f, _Float16* __restrict__ Mt_aug,
                            float* __restrict__ bias_mg) {
    const int wid = blockIdx.x * 4 + (threadIdx.x >> 6);
    const int lane = threadIdx.x & 63;
    if (wid < 768) {                 // w1[wid] = WqT[wid,:]·bk
        float s = 0.f;
        for (int k = 0; k < 12; ++k) s += (float)WqT[(size_t)wid * 768 + lane + 64 * k] * bk[lane + 64 * k];
        for (int o = 32; o; o >>= 1) s += __shfl_xor(s, o);
        if (lane == 0) Mt_aug[(size_t)768 * 768 + wid] = (_Float16)s;
    } else if (wid < 1536) {         // w2[n] = WkT[n,:]·bq
        const int n = wid - 768;
        float s = 0.f;
        for (int k = 0; k < 12; ++k) s += (float)WkT[(size_t)n * 768 + lane + 64 * k] * bq[lane + 64 * k];
        for (int o = 32; o; o >>= 1) s += __shfl_xor(s, o);
        if (lane == 0) w2f[n] = s;
    } else if (wid == 1536) {        // c0 -> bias_mg[768], 1 -> [769], 0 -> 770..799
        float s = 0.f;
        for (int k = 0; k < 12; ++k) s += bq[lane + 64 * k] * bk[lane + 64 * k];
        for (int o = 32; o; o >>= 1) s += __shfl_xor(s, o);
        if (lane < 32) {
            float v = 0.f;
            if (lane == 0) v = s;
            if (lane == 1) v = 1.f;
            bias_mg[768 + lane] = v;
        }
    } else if (wid < 1560) {         // bias_mg: zeros 0..767 ; bv -> 800..1376 ; 0 pads
        const int i = (wid - 1537) * 64 + lane;     // [0,1472)
        if (i < 768) bias_mg[i] = 0.f;
        else {
            const int j = i + 32;                   // 800..1503
            if (j < 1408) bias_mg[j] = (j < 1377) ? bv[j - 800] : 0.f;
        }
    } else if (wid < 1591) {         // zero Mt_aug rows 769..799
        const int r = 769 + (wid - 1560);
        for (int k = 0; k < 12; ++k) Mt_aug[(size_t)r * 768 + lane + 64 * k] = (_Float16)0.f;
    }
}

// e f32 [rows,768] -> e' f16 [rows,800]: cvt + col768=1 + col769=e·w2 + 770..799=0
__global__ void cvt_e_aug_kernel(const float* __restrict__ e, const float* __restrict__ w2f,
                                 _Float16* __restrict__ dst, int rows) {
    const int wpb = blockDim.x >> 6;
    int wid = blockIdx.x * wpb + (threadIdx.x >> 6);
    const int nw = gridDim.x * wpb;
    const int lane = threadIdx.x & 63;
    for (int s = wid; s < rows; s += nw) {
        const float4* er = (const float4*)(e + (size_t)s * 768);
        _Float16* dr = dst + (size_t)s * 800;
        float dot = 0.f;
#pragma unroll
        for (int k = 0; k < 3; ++k) {
            const int idx = lane + 64 * k;
            const float4 v = er[idx];
            const float4 w = ((const float4*)w2f)[idx];
            dot += v.x * w.x + v.y * w.y + v.z * w.z + v.w * w.w;
            f16x4 h;
            h[0] = (_Float16)v.x; h[1] = (_Float16)v.y;
            h[2] = (_Float16)v.z; h[3] = (_Float16)v.w;
            *(f16x4*)(dr + 4 * idx) = h;
        }
        for (int o = 32; o; o >>= 1) dot += __shfl_xor(dot, o);
        if (lane < 32) {
            _Float16 v = (_Float16)0.f;
            if (lane == 0) v = (_Float16)1.f;
            if (lane == 1) v = (_Float16)dot;
            dr[768 + lane] = v;
        }
    }
}

__device__ __forceinline__ void gload16(const _Float16* g, _Float16* l) {
    __builtin_amdgcn_global_load_lds(
        (const __attribute__((address_space(1))) unsigned int*)(g),
        (__attribute__((address_space(3))) unsigned int*)(l),
        16, 0, 0);
}

// -------- 128x128 / BK=32 / 3-stage counted-vmcnt GEMM (R7, proven) ----------
template<bool TANH, bool OUT_F16, bool BIAS, int MODE>
__global__ __launch_bounds__(256)
void gemm_nt_f16(const _Float16* __restrict__ A, const _Float16* __restrict__ Bt,
                 const float* __restrict__ bias, void* __restrict__ Cp,
                 int M, int Nreal, int Nstore, int K,
                 int lda, int ldb, int ldc, int nTileN, int nTiles,
                 long long sA, long long sB, long long sC)
{
    __shared__ __align__(16) _Float16 lds[3 * 8192];

    int bid = blockIdx.x;
    int z, tm, tn;
    if (MODE == 0) {
        const int nwg = gridDim.x;
        const int q8 = nwg >> 3, r8 = nwg & 7;
        const int xcd = bid & 7, loc = bid >> 3;
        bid = (xcd < r8 ? xcd * (q8 + 1) : r8 * (q8 + 1) + (xcd - r8) * q8) + loc;
        z = 0;
        tm = bid / nTileN; tn = bid - tm * nTileN;
    } else {
        const int xcd = bid & 7, idx = bid >> 3;
        const int g = idx / nTiles, tile = idx - g * nTiles;
        z = g * 8 + xcd;
        tm = tile / nTileN; tn = tile - tm * nTileN;
    }
    const int m0 = tm << 7, n0 = tn << 7;

    const _Float16* Az = A + (size_t)z * sA;
    const _Float16* Bz = Bt + (size_t)z * sB;

    const int tid = threadIdx.x;
    const int lane = tid & 63;
    const int wid = tid >> 6;
    const int wm = wid >> 1, wn = wid & 1;

    const int r0 = tid >> 2;
    const int c0 = (((tid & 3) ^ ((tid >> 3) & 3)) << 3);
    const int rA0 = (m0 + r0      < M ? m0 + r0      : M - 1);
    const int rA1 = (m0 + r0 + 64 < M ? m0 + r0 + 64 : M - 1);
    const int rB0 = (n0 + r0      < Nreal ? n0 + r0      : Nreal - 1);
    const int rB1 = (n0 + r0 + 64 < Nreal ? n0 + r0 + 64 : Nreal - 1);
    const _Float16* pA0 = Az + (size_t)rA0 * lda + c0;
    const _Float16* pA1 = Az + (size_t)rA1 * lda + c0;
    const _Float16* pB0 = Bz + (size_t)rB0 * ldb + c0;
    const _Float16* pB1 = Bz + (size_t)rB1 * ldb + c0;

    const int o0 = tid * 8, o1 = (tid + 256) * 8;

    const int rr = lane & 15;
    const int hh = lane >> 4;
    const int sw = (rr >> 1) & 3;
    const int fAo = ((wm * 64 + rr) * 4 + (hh ^ sw)) * 8;
    const int fBo = ((wn * 64 + rr) * 4 + (hh ^ sw)) * 8;

    const f32x4 z4 = {0.f, 0.f, 0.f, 0.f};
    f32x4 acc[4][4];
#pragma unroll
    for (int i = 0; i < 4; ++i)
#pragma unroll
        for (int j = 0; j < 4; ++j) acc[i][j] = z4;

    const int nt = K >> 5;

#define STAGE(si, kt)                                              \
    do {                                                           \
        _Float16* base_ = lds + (si) * 8192;                       \
        const int ko_ = (kt) << 5;                                 \
        gload16(pA0 + ko_, base_ + o0);                            \
        gload16(pA1 + ko_, base_ + o1);                            \
        gload16(pB0 + ko_, base_ + 4096 + o0);                     \
        gload16(pB1 + ko_, base_ + 4096 + o1);                     \
    } while (0)

#define COMPUTE(si)                                                            \
    do {                                                                       \
        const _Float16* cA_ = lds + (si) * 8192;                               \
        const _Float16* cB_ = cA_ + 4096;                                      \
        f16x8 a_[4], b_[4];                                                    \
        _Pragma("unroll")                                                      \
        for (int mi = 0; mi < 4; ++mi) a_[mi] = *(const f16x8*)(cA_ + fAo + mi * 512); \
        _Pragma("unroll")                                                      \
        for (int ni = 0; ni < 4; ++ni) b_[ni] = *(const f16x8*)(cB_ + fBo + ni * 512); \
        _Pragma("unroll")                                                      \
        for (int mi = 0; mi < 4; ++mi)                                         \
            _Pragma("unroll")                                                  \
            for (int ni = 0; ni < 4; ++ni)                                     \
                acc[mi][ni] = __builtin_amdgcn_mfma_f32_16x16x32_f16(          \
                    a_[mi], b_[ni], acc[mi][ni], 0, 0, 0);                     \
    } while (0)

    STAGE(0, 0);
    STAGE(1, 1);

    for (int j = 0; j < nt - 1; ++j) {
        asm volatile("s_waitcnt vmcnt(4)" ::: "memory");
        __builtin_amdgcn_s_barrier();
        __builtin_amdgcn_sched_barrier(0);
        if (j + 2 < nt) STAGE((j + 2) % 3, j + 2);
        COMPUTE(j % 3);
    }
    asm volatile("s_waitcnt vmcnt(0)" ::: "memory");
    __builtin_amdgcn_s_barrier();
    __builtin_amdgcn_sched_barrier(0);
    COMPUTE((nt - 1) % 3);

#undef STAGE
#undef COMPUTE

    const int cr0 = (lane >> 4) << 2;
    const int cc = lane & 15;
    float*    Cf = (float*)Cp    + (size_t)z * sC;
    _Float16* Ch = (_Float16*)Cp + (size_t)z * sC;
#pragma unroll
    for (int mi = 0; mi < 4; ++mi) {
#pragma unroll
        for (int ni = 0; ni < 4; ++ni) {
            const int gc = n0 + wn * 64 + ni * 16 + cc;
            if (gc >= Nstore) continue;
            const bool real = gc < Nreal;
            float bb = 0.f;
            if (BIAS) bb = real ? bias[gc] : 0.f;
#pragma unroll
            for (int r = 0; r < 4; ++r) {
                const int gr = m0 + wm * 64 + mi * 16 + cr0 + r;
                if (gr >= M) continue;
                float x = real ? (acc[mi][ni][r] + bb) : 0.f;
                if (TANH) x = tanhf(x);
                if (OUT_F16) Ch[(size_t)gr * ldc + gc] = (_Float16)x;
                else         Cf[(size_t)gr * ldc + gc] = x;
            }
        }
    }
}

extern "C" void kernel_launch(void* const* d_in, const int* in_sizes, int n_in,
                              void* d_out, int out_size, void* d_ws, size_t ws_size,
                              hipStream_t stream)
{
    const float* b  = (const float*)d_in[0];
    const float* e  = (const float*)d_in[1];
    const float* Wq = (const float*)d_in[2];
    const float* bq = (const float*)d_in[3];
    const float* Wk = (const float*)d_in[4];
    const float* bk = (const float*)d_in[5];
    const float* Wv = (const float*)d_in[6];
    const float* bv = (const float*)d_in[7];
    float* out = (float*)d_out;

    const int BT = 36928, T = 577, S = 577, Sp = 608, Kb = 800;
    const int Nmg = 1408;   // merged B rows: 800 aug + 608 v-slot

    // ws layout (f16 units): ~212.5 MB total
    _Float16* WqT_h  = (_Float16*)d_ws;                      // 589824
    _Float16* WkT_h  = WqT_h + 589824;                       // 589824
    _Float16* Mt_aug = WkT_h + 589824;                       // 800*768 (B rows 0..799)
    _Float16* Wv_h   = Mt_aug + 614400;                      // 577*768 (B rows 800..1376)
    float*    bias_mg = (float*)(Wv_h + 443136);             // 1408 f32 (2816 hw)
    float*    w2f     = (float*)((_Float16*)bias_mg + 2816); // 768 f32 (1536 hw)
    _Float16* S1    = (_Float16*)w2f + 1536;                 // b_h [BT,768] then e' [BT,800]
    _Float16* S_big = S1 + (size_t)BT * Kb;                  // [BT,1408]
    _Float16* S4    = S_big + (size_t)BT * Nmg;              // attn [BT,608]

    // weight preprocessing
    cvtT2_kernel<<<dim3(24, 24, 2), 256, 0, stream>>>(Wq, WqT_h, Wk, WkT_h);
    cvt8_kernel<<<217, 256, 0, stream>>>(Wv, Wv_h, 55392);
    prep_kernel<<<398, 256, 0, stream>>>(WqT_h, WkT_h, bq, bk, bv, w2f, Mt_aug, bias_mg);
    // Mt = NT(WkT, WqT)  [768x768] -> Mt_aug rows 0..767
    gemm_nt_f16<false, true, false, 0><<<dim3(36, 1, 1), 256, 0, stream>>>(
        WkT_h, WqT_h, nullptr, Mt_aug, 768, 768, 768, 768, 768, 768, 768, 6, 0, 0, 0, 0);

    // b -> f16
    cvt8_kernel<<<2048, 256, 0, stream>>>(b, S1, 3545088);
    // S_big = b_h @ B_merged^T + bias_mg   [BT,1408]  (11 N-tiles, 0 waste)
    gemm_nt_f16<false, true, true, 0><<<dim3(3179, 1, 1), 256, 0, stream>>>(
        S1, Mt_aug, bias_mg, S_big, BT, 1377, Nmg, 768, 768, 768, Nmg, 11, 0, 0, 0, 0);
    // e' (overwrites b_h, dead)
    cvt_e_aug_kernel<<<2048, 256, 0, stream>>>(e, w2f, S1, BT);
    // attn = tanh(NT(S_big[:,0:800], e'))  batched [64][577,608], K=800
    gemm_nt_f16<true, true, false, 1><<<dim3(1600, 1, 1), 256, 0, stream>>>(
        S_big, S1, nullptr, S4, T, S, Sp, Kb, Nmg, Kb, Sp, 5, 25,
        (long long)T * Nmg, (long long)T * Kb, (long long)T * Sp);
    // out = NT(attn, S_big[:,800:1408])  batched [64][577,577] f32, K=608
    gemm_nt_f16<false, false, false, 1><<<dim3(1600, 1, 1), 256, 0, stream>>>(
        S4, S_big + 800, nullptr, out, T, T, T, Sp, Sp, Nmg, T, 5, 25,
        (long long)T * Sp, (long long)T * Nmg, (long long)T * T);
}